// Round 1
// baseline (3458.472 us; speedup 1.0000x reference)
//
#include <hip/hip_runtime.h>
#include <math.h>

#define HWQ 625      // 25*25
#define NPOSQ 390625 // 625*625
#define NB 4
#define NCH 1024

// ---------------- pack weights (direct + tap-permuted copies) ----------------
__global__ void pack_weights_kernel(
    const float* __restrict__ W1, const float* __restrict__ b1,
    const float* __restrict__ W2, const float* __restrict__ b2,
    const float* __restrict__ W3, const float* __restrict__ b3,
    float* __restrict__ WL1, float* __restrict__ WL2, float* __restrict__ WL3,
    float* __restrict__ bL1, float* __restrict__ bL2, float* __restrict__ bL3)
{
    int t = blockIdx.x * blockDim.x + threadIdx.x;
    // tap = d1*27 + d2*9 + d3*3 + d4 ; permuted source tap = d3*27 + d4*9 + d1*3 + d2
    if (t < 1620) { // WL1 [20][81]
        int co = t / 81, tap = t % 81;
        int d1 = tap / 27, d2 = (tap / 9) % 3, d3 = (tap / 3) % 3, d4 = tap % 3;
        int ptap = d3 * 27 + d4 * 9 + d1 * 3 + d2;
        WL1[t] = (co < 10) ? W1[co * 81 + tap] : W1[(co - 10) * 81 + ptap];
    }
    if (t < 16200) { // WL2 [2][10][10][81]
        int g = t / 8100; int rem = t - g * 8100;
        int co = rem / 810; int rem2 = rem - co * 810;
        int ci = rem2 / 81; int tap = rem2 - ci * 81;
        int d1 = tap / 27, d2 = (tap / 9) % 3, d3 = (tap / 3) % 3, d4 = tap % 3;
        int ptap = d3 * 27 + d4 * 9 + d1 * 3 + d2;
        WL2[t] = W2[(co * 10 + ci) * 81 + (g == 0 ? tap : ptap)];
    }
    if (t < 1620) { // WL3 [2][1][10][81]
        int g = t / 810; int rem = t - g * 810;
        int ci = rem / 81; int tap = rem - ci * 81;
        int d1 = tap / 27, d2 = (tap / 9) % 3, d3 = (tap / 3) % 3, d4 = tap % 3;
        int ptap = d3 * 27 + d4 * 9 + d1 * 3 + d2;
        WL3[t] = W3[ci * 81 + (g == 0 ? tap : ptap)];
    }
    if (t < 20) { bL1[t] = b1[t % 10]; bL2[t] = b2[t % 10]; }
    if (t < 2)  { bL3[t] = b3[0]; }
}

// ---------------- inverse L2 norms over channel dim ----------------
__global__ void invnorm_kernel(const float* __restrict__ fA, const float* __restrict__ fB,
                               float* __restrict__ invA, float* __restrict__ invB)
{
    int idx = blockIdx.x * blockDim.x + threadIdx.x;
    if (idx >= NB * HWQ) return;
    const float* f = blockIdx.y ? fB : fA;
    float* o = blockIdx.y ? invB : invA;
    int b = idx / HWQ, m = idx - b * HWQ;
    const float* p = f + (size_t)b * NCH * HWQ + m;
    float s = 0.f;
    for (int c = 0; c < NCH; c += 4) {
        float x0 = p[(c + 0) * HWQ], x1 = p[(c + 1) * HWQ];
        float x2 = p[(c + 2) * HWQ], x3 = p[(c + 3) * HWQ];
        s += x0 * x0 + x1 * x1 + x2 * x2 + x3 * x3;
    }
    o[idx] = 1.0f / sqrtf(s + 1e-6f);
}

// ---------------- correlation GEMM: corr[b,m,n] = relu(dot*invA*invB) normalized ----------------
__global__ __launch_bounds__(256) void corr_gemm_kernel(
    const float* __restrict__ fA, const float* __restrict__ fB,
    const float* __restrict__ invA, const float* __restrict__ invB,
    float* __restrict__ corr)
{
    __shared__ float As[16][64];
    __shared__ float Bs[16][64];
    const int b = blockIdx.z;
    const int m0 = blockIdx.y * 64, n0 = blockIdx.x * 64;
    const int tid = threadIdx.x;
    const int tx = tid & 15, ty = tid >> 4;
    float acc[4][4] = {};
    const float* Ab = fA + (size_t)b * NCH * HWQ;
    const float* Bb = fB + (size_t)b * NCH * HWQ;
    for (int k0 = 0; k0 < NCH; k0 += 16) {
        for (int i = tid; i < 1024; i += 256) {
            int k = i >> 6, mm = i & 63;
            int gm = m0 + mm, gn = n0 + mm;
            As[k][mm] = (gm < HWQ) ? Ab[(k0 + k) * HWQ + gm] : 0.0f;
            Bs[k][mm] = (gn < HWQ) ? Bb[(k0 + k) * HWQ + gn] : 0.0f;
        }
        __syncthreads();
#pragma unroll
        for (int k = 0; k < 16; ++k) {
            float4 a4 = *(const float4*)&As[k][ty * 4];
            float4 b4 = *(const float4*)&Bs[k][tx * 4];
            float av[4] = {a4.x, a4.y, a4.z, a4.w};
            float bv[4] = {b4.x, b4.y, b4.z, b4.w};
#pragma unroll
            for (int i = 0; i < 4; ++i)
#pragma unroll
                for (int j = 0; j < 4; ++j)
                    acc[i][j] = fmaf(av[i], bv[j], acc[i][j]);
        }
        __syncthreads();
    }
#pragma unroll
    for (int i = 0; i < 4; ++i) {
        int m = m0 + ty * 4 + i;
        if (m >= HWQ) continue;
        float ia = invA[b * HWQ + m];
#pragma unroll
        for (int j = 0; j < 4; ++j) {
            int n = n0 + tx * 4 + j;
            if (n >= HWQ) continue;
            float v = acc[i][j] * ia * invB[b * HWQ + n];
            v = fmaxf(v, 0.0f);
            v = v / sqrtf(v * v + 1e-6f);
            corr[((size_t)b * HWQ + m) * HWQ + n] = v;
        }
    }
}

// ---------------- mutual matching helpers ----------------
__global__ void rowmax_kernel(const float* __restrict__ s, float* __restrict__ rmax)
{
    int row = blockIdx.x * 4 + (threadIdx.x >> 6);
    int lane = threadIdx.x & 63;
    if (row >= NB * HWQ) return;
    const float* p = s + (size_t)row * HWQ;
    float v = -1e30f;
    for (int n = lane; n < HWQ; n += 64) v = fmaxf(v, p[n]);
    for (int off = 32; off; off >>= 1) v = fmaxf(v, __shfl_xor(v, off));
    if (lane == 0) rmax[row] = v;
}

__global__ void colmax_kernel(const float* __restrict__ s, float* __restrict__ cmax)
{
    int b = blockIdx.x;
    int col = blockIdx.y * 128 + threadIdx.x;
    if (col >= HWQ) return;
    const float* p = s + (size_t)b * NPOSQ + col;
    float v = -1e30f;
    for (int m = 0; m < HWQ; ++m) v = fmaxf(v, p[m * HWQ]);
    cmax[b * HWQ + col] = v;
}

__global__ void mm_apply_kernel(const float* __restrict__ s, const float* __restrict__ rmax,
                                const float* __restrict__ cmax, float* __restrict__ out)
{
    int idx = blockIdx.x * blockDim.x + threadIdx.x;
    if (idx >= NB * NPOSQ) return;
    int b = idx / NPOSQ, rem = idx - b * NPOSQ;
    int m = rem / HWQ, n = rem - m * HWQ;
    float v = s[idx];
    out[idx] = v * v * v / ((rmax[b * HWQ + m] + 1e-5f) * (cmax[b * HWQ + n] + 1e-5f));
}

__global__ void sum2_kernel(const float* __restrict__ x3, float* __restrict__ s)
{
    int idx = blockIdx.x * blockDim.x + threadIdx.x;
    if (idx >= NB * NPOSQ) return;
    int b = idx / NPOSQ, rem = idx - b * NPOSQ;
    s[idx] = x3[(size_t)(b * 2) * NPOSQ + rem] + x3[(size_t)(b * 2 + 1) * NPOSQ + rem];
}

// ---------------- conv4d, single batch, grouped ----------------
// in:  [G*CIN_G][NPOSQ] slab for this batch
// w:   [((g*COUT_G+co)*CIN_G+ci)*81 + tap]
// out: [G*COUT_G][NPOSQ]
template <int CIN_G, int COUT_G>
__global__ __launch_bounds__(640) void conv4d_kernel(
    const float* __restrict__ in, const float* __restrict__ w,
    const float* __restrict__ bias, float* __restrict__ out)
{
    __shared__ float sp[6561]; // 9 x 27 x 27
    const int f12 = blockIdx.x;
    const int g = blockIdx.y;
    const int f1 = f12 / 25, f2 = f12 - f1 * 25;
    const int tid = threadIdx.x;
    const bool active = tid < 625;
    const int pt = active ? tid : 624;
    const int r = pt / 25, c = pt - r * 25;

    float acc[COUT_G];
#pragma unroll
    for (int co = 0; co < COUT_G; ++co) acc[co] = bias[g * COUT_G + co];

    for (int ci = 0; ci < CIN_G; ++ci) {
        const float* ip = in + (size_t)(g * CIN_G + ci) * NPOSQ;
        __syncthreads();
        for (int i = tid; i < 6561; i += 640) {
            int e = i / 729; int rem = i - e * 729;
            int rr = rem / 27; int cc = rem - rr * 27;
            int f1n = f1 + e / 3 - 1, f2n = f2 + (e % 3) - 1;
            int f3 = rr - 1, f4 = cc - 1;
            float v = 0.0f;
            if (((unsigned)f1n < 25u) & ((unsigned)f2n < 25u) &
                ((unsigned)f3 < 25u) & ((unsigned)f4 < 25u))
                v = ip[(f1n * 25 + f2n) * HWQ + f3 * 25 + f4];
            sp[i] = v;
        }
        __syncthreads();
        const float* wci = w + ((size_t)g * COUT_G * CIN_G + ci) * 81;
        for (int e = 0; e < 9; ++e) {
            const int base = e * 729 + r * 27 + c;
#pragma unroll
            for (int t34 = 0; t34 < 9; ++t34) {
                const int d3 = t34 / 3, d4 = t34 - d3 * 3;
                float v = sp[base + d3 * 27 + d4];
#pragma unroll
                for (int co = 0; co < COUT_G; ++co)
                    acc[co] = fmaf(v, wci[(size_t)co * CIN_G * 81 + e * 9 + t34], acc[co]);
            }
        }
    }
    if (active) {
#pragma unroll
        for (int co = 0; co < COUT_G; ++co) {
            float v = fmaxf(acc[co], 0.0f); // relu of every stack layer
            out[(size_t)(g * COUT_G + co) * NPOSQ + f12 * 625 + pt] = v;
        }
    }
}

// ---------------- launch ----------------
extern "C" void kernel_launch(void* const* d_in, const int* in_sizes, int n_in,
                              void* d_out, int out_size, void* d_ws, size_t ws_size,
                              hipStream_t stream)
{
    const float* fA = (const float*)d_in[0];
    const float* fB = (const float*)d_in[1];
    const float* W1 = (const float*)d_in[2];
    const float* b1 = (const float*)d_in[3];
    const float* W2 = (const float*)d_in[4];
    const float* b2 = (const float*)d_in[5];
    const float* W3 = (const float*)d_in[6];
    const float* b3 = (const float*)d_in[7];
    float* out = (float*)d_out;
    float* ws = (float*)d_ws;

    float* invA = ws + 0;        // 2500
    float* invB = ws + 2500;     // 2500
    float* rmax = ws + 5000;     // 2500
    float* cmax = ws + 7500;     // 2500
    float* WL1  = ws + 10000;    // 1620
    float* WL2  = ws + 11620;    // 16200
    float* WL3  = ws + 27820;    // 1620
    float* bL1  = ws + 29440;    // 20
    float* bL2  = ws + 29460;    // 20
    float* bL3  = ws + 29480;    // 2
    float* corr = ws + 40000;    // 1562500  (also x0 after in-place mm)
    float* sbuf = ws + 1602504;  // 1562500
    float* x1   = ws + 3170000;  // 7812500  (20ch, one batch)
    float* x2   = ws + 11000000; // 7812500  (20ch, one batch)
    float* x3   = ws + 18820000; // 3125000  ([B][2][NPOSQ])
    // total ~21.95M floats = ~88 MB

    hipLaunchKernelGGL(pack_weights_kernel, dim3(64), dim3(256), 0, stream,
                       W1, b1, W2, b2, W3, b3, WL1, WL2, WL3, bL1, bL2, bL3);
    hipLaunchKernelGGL(invnorm_kernel, dim3(10, 2), dim3(256), 0, stream, fA, fB, invA, invB);
    hipLaunchKernelGGL(corr_gemm_kernel, dim3(10, 10, 4), dim3(256), 0, stream,
                       fA, fB, invA, invB, corr);
    hipLaunchKernelGGL(rowmax_kernel, dim3(625), dim3(256), 0, stream, corr, rmax);
    hipLaunchKernelGGL(colmax_kernel, dim3(4, 5), dim3(128), 0, stream, corr, cmax);
    hipLaunchKernelGGL(mm_apply_kernel, dim3(6104), dim3(256), 0, stream, corr, rmax, cmax, corr);

    for (int b = 0; b < NB; ++b) {
        hipLaunchKernelGGL((conv4d_kernel<1, 20>), dim3(625, 1), dim3(640), 0, stream,
                           corr + (size_t)b * NPOSQ, WL1, bL1, x1);
        hipLaunchKernelGGL((conv4d_kernel<10, 10>), dim3(625, 2), dim3(640), 0, stream,
                           x1, WL2, bL2, x2);
        hipLaunchKernelGGL((conv4d_kernel<10, 1>), dim3(625, 2), dim3(640), 0, stream,
                           x2, WL3, bL3, x3 + (size_t)b * 2 * NPOSQ);
    }

    hipLaunchKernelGGL(sum2_kernel, dim3(6104), dim3(256), 0, stream, x3, sbuf);
    hipLaunchKernelGGL(rowmax_kernel, dim3(625), dim3(256), 0, stream, sbuf, rmax);
    hipLaunchKernelGGL(colmax_kernel, dim3(4, 5), dim3(128), 0, stream, sbuf, cmax);
    hipLaunchKernelGGL(mm_apply_kernel, dim3(6104), dim3(256), 0, stream, sbuf, rmax, cmax, out);
}

// Round 2
// 2195.132 us; speedup vs baseline: 1.5755x; 1.5755x over previous
//
#include <hip/hip_runtime.h>
#include <math.h>

#define HWQ 625      // 25*25
#define NPOSQ 390625 // 625*625
#define NB 4
#define NCH 1024

// ---------------- pack weights (direct + tap-permuted copies) ----------------
__global__ void pack_weights_kernel(
    const float* __restrict__ W1, const float* __restrict__ b1,
    const float* __restrict__ W2, const float* __restrict__ b2,
    const float* __restrict__ W3, const float* __restrict__ b3,
    float* __restrict__ WL1, float* __restrict__ WL2, float* __restrict__ WL3,
    float* __restrict__ bL1, float* __restrict__ bL2, float* __restrict__ bL3)
{
    int t = blockIdx.x * blockDim.x + threadIdx.x;
    // tap = d1*27 + d2*9 + d3*3 + d4 ; permuted source tap = d3*27 + d4*9 + d1*3 + d2
    if (t < 1620) { // WL1 [20][81]
        int co = t / 81, tap = t % 81;
        int d1 = tap / 27, d2 = (tap / 9) % 3, d3 = (tap / 3) % 3, d4 = tap % 3;
        int ptap = d3 * 27 + d4 * 9 + d1 * 3 + d2;
        WL1[t] = (co < 10) ? W1[co * 81 + tap] : W1[(co - 10) * 81 + ptap];
    }
    if (t < 16200) { // WL2 [2][10][10][81]
        int g = t / 8100; int rem = t - g * 8100;
        int co = rem / 810; int rem2 = rem - co * 810;
        int ci = rem2 / 81; int tap = rem2 - ci * 81;
        int d1 = tap / 27, d2 = (tap / 9) % 3, d3 = (tap / 3) % 3, d4 = tap % 3;
        int ptap = d3 * 27 + d4 * 9 + d1 * 3 + d2;
        WL2[t] = W2[(co * 10 + ci) * 81 + (g == 0 ? tap : ptap)];
    }
    if (t < 1620) { // WL3 [2][1][10][81]
        int g = t / 810; int rem = t - g * 810;
        int ci = rem / 81; int tap = rem - ci * 81;
        int d1 = tap / 27, d2 = (tap / 9) % 3, d3 = (tap / 3) % 3, d4 = tap % 3;
        int ptap = d3 * 27 + d4 * 9 + d1 * 3 + d2;
        WL3[t] = W3[ci * 81 + (g == 0 ? tap : ptap)];
    }
    if (t < 20) { bL1[t] = b1[t % 10]; bL2[t] = b2[t % 10]; }
    if (t < 2)  { bL3[t] = b3[0]; }
}

// ---------------- inverse L2 norms over channel dim ----------------
__global__ void invnorm_kernel(const float* __restrict__ fA, const float* __restrict__ fB,
                               float* __restrict__ invA, float* __restrict__ invB)
{
    int idx = blockIdx.x * blockDim.x + threadIdx.x;
    if (idx >= NB * HWQ) return;
    const float* f = blockIdx.y ? fB : fA;
    float* o = blockIdx.y ? invB : invA;
    int b = idx / HWQ, m = idx - b * HWQ;
    const float* p = f + (size_t)b * NCH * HWQ + m;
    float s = 0.f;
    for (int c = 0; c < NCH; c += 4) {
        float x0 = p[(c + 0) * HWQ], x1 = p[(c + 1) * HWQ];
        float x2 = p[(c + 2) * HWQ], x3 = p[(c + 3) * HWQ];
        s += x0 * x0 + x1 * x1 + x2 * x2 + x3 * x3;
    }
    o[idx] = 1.0f / sqrtf(s + 1e-6f);
}

// ---------------- correlation GEMM ----------------
__global__ __launch_bounds__(256) void corr_gemm_kernel(
    const float* __restrict__ fA, const float* __restrict__ fB,
    const float* __restrict__ invA, const float* __restrict__ invB,
    float* __restrict__ corr)
{
    __shared__ float As[16][64];
    __shared__ float Bs[16][64];
    const int b = blockIdx.z;
    const int m0 = blockIdx.y * 64, n0 = blockIdx.x * 64;
    const int tid = threadIdx.x;
    const int tx = tid & 15, ty = tid >> 4;
    float acc[4][4] = {};
    const float* Ab = fA + (size_t)b * NCH * HWQ;
    const float* Bb = fB + (size_t)b * NCH * HWQ;
    for (int k0 = 0; k0 < NCH; k0 += 16) {
        for (int i = tid; i < 1024; i += 256) {
            int k = i >> 6, mm = i & 63;
            int gm = m0 + mm, gn = n0 + mm;
            As[k][mm] = (gm < HWQ) ? Ab[(k0 + k) * HWQ + gm] : 0.0f;
            Bs[k][mm] = (gn < HWQ) ? Bb[(k0 + k) * HWQ + gn] : 0.0f;
        }
        __syncthreads();
#pragma unroll
        for (int k = 0; k < 16; ++k) {
            float4 a4 = *(const float4*)&As[k][ty * 4];
            float4 b4 = *(const float4*)&Bs[k][tx * 4];
            float av[4] = {a4.x, a4.y, a4.z, a4.w};
            float bv[4] = {b4.x, b4.y, b4.z, b4.w};
#pragma unroll
            for (int i = 0; i < 4; ++i)
#pragma unroll
                for (int j = 0; j < 4; ++j)
                    acc[i][j] = fmaf(av[i], bv[j], acc[i][j]);
        }
        __syncthreads();
    }
#pragma unroll
    for (int i = 0; i < 4; ++i) {
        int m = m0 + ty * 4 + i;
        if (m >= HWQ) continue;
        float ia = invA[b * HWQ + m];
#pragma unroll
        for (int j = 0; j < 4; ++j) {
            int n = n0 + tx * 4 + j;
            if (n >= HWQ) continue;
            float v = acc[i][j] * ia * invB[b * HWQ + n];
            v = fmaxf(v, 0.0f);
            v = v / sqrtf(v * v + 1e-6f);
            corr[((size_t)b * HWQ + m) * HWQ + n] = v;
        }
    }
}

// ---------------- mutual matching helpers ----------------
__global__ void rowmax_kernel(const float* __restrict__ s, float* __restrict__ rmax)
{
    int row = blockIdx.x * 4 + (threadIdx.x >> 6);
    int lane = threadIdx.x & 63;
    if (row >= NB * HWQ) return;
    const float* p = s + (size_t)row * HWQ;
    float v = -1e30f;
    for (int n = lane; n < HWQ; n += 64) v = fmaxf(v, p[n]);
    for (int off = 32; off; off >>= 1) v = fmaxf(v, __shfl_xor(v, off));
    if (lane == 0) rmax[row] = v;
}

__global__ void colmax_kernel(const float* __restrict__ s, float* __restrict__ cmax)
{
    int b = blockIdx.x;
    int col = blockIdx.y * 128 + threadIdx.x;
    if (col >= HWQ) return;
    const float* p = s + (size_t)b * NPOSQ + col;
    float v = -1e30f;
    for (int m = 0; m < HWQ; ++m) v = fmaxf(v, p[m * HWQ]);
    cmax[b * HWQ + col] = v;
}

__global__ void mm_apply_kernel(const float* __restrict__ s, const float* __restrict__ rmax,
                                const float* __restrict__ cmax, float* __restrict__ out)
{
    int idx = blockIdx.x * blockDim.x + threadIdx.x;
    if (idx >= NB * NPOSQ) return;
    int b = idx / NPOSQ, rem = idx - b * NPOSQ;
    int m = rem / HWQ, n = rem - m * HWQ;
    float v = s[idx];
    out[idx] = v * v * v / ((rmax[b * HWQ + m] + 1e-5f) * (cmax[b * HWQ + n] + 1e-5f));
}

__global__ void sum2_kernel(const float* __restrict__ x3, float* __restrict__ s)
{
    int idx = blockIdx.x * blockDim.x + threadIdx.x;
    if (idx >= NB * NPOSQ) return;
    int b = idx / NPOSQ, rem = idx - b * NPOSQ;
    s[idx] = x3[(size_t)(b * 2) * NPOSQ + rem] + x3[(size_t)(b * 2 + 1) * NPOSQ + rem];
}

// ---------------- conv4d v2: 2x2 (f3,f4) register tile per thread ----------------
// in:  [G*CIN_G][NPOSQ] slab for this batch
// w:   [((g*COUT_G+co)*CIN_G+ci)*81 + tap]
// out: [G*COUT_G][NPOSQ]
// Block: 192 threads, 169 active (13x13 tiles of 2x2), one (f1,f2) per block.
// LDS: 9 planes of 28x28 (f3,f4 in -1..26, rows/cols 26,27 stay zero).
template <int CIN_G, int COUT_G>
__global__ __launch_bounds__(192) void conv4d_kernel(
    const float* __restrict__ in, const float* __restrict__ w,
    const float* __restrict__ bias, float* __restrict__ out)
{
    __shared__ float sp[9 * 784]; // 9 x 28 x 28 = 28224 B
    const int f12 = blockIdx.x;
    const int g = blockIdx.y;
    const int f1 = f12 / 25, f2 = f12 - f1 * 25;
    const int tid = threadIdx.x;

    // zero LDS once (pads stay zero forever; interior rewritten per ci)
    for (int i = tid; i < 9 * 784; i += 192) sp[i] = 0.0f;

    const int tt = (tid < 169) ? tid : 0;
    const int ty = tt / 13, tx = tt - ty * 13;
    const int r0 = ty * 2, c0 = tx * 2;

    float acc[COUT_G][4];
#pragma unroll
    for (int co = 0; co < COUT_G; ++co) {
        float bv = bias[g * COUT_G + co];
        acc[co][0] = bv; acc[co][1] = bv; acc[co][2] = bv; acc[co][3] = bv;
    }

#pragma unroll 1
    for (int ci = 0; ci < CIN_G; ++ci) {
        const float* ip = in + (size_t)(g * CIN_G + ci) * NPOSQ;
        __syncthreads(); // previous compute done before overwrite
        for (int i = tid; i < 5625; i += 192) {
            int e = i / 625, q = i - e * 625;
            int d1 = e / 3, d2 = e - d1 * 3;
            int f1n = f1 + d1 - 1, f2n = f2 + d2 - 1;
            float v = 0.0f;
            if (((unsigned)f1n < 25u) & ((unsigned)f2n < 25u))
                v = ip[(f1n * 25 + f2n) * HWQ + q];
            int rr = q / 25, cc = q - rr * 25;
            sp[e * 784 + (rr + 1) * 28 + (cc + 1)] = v;
        }
        __syncthreads();
        const float* wci = w + ((size_t)(g * COUT_G) * CIN_G + ci) * 81;
#pragma unroll 1
        for (int e = 0; e < 9; ++e) {
            float win[16];
            const int base = e * 784 + r0 * 28 + c0;
#pragma unroll
            for (int a = 0; a < 4; ++a)
#pragma unroll
                for (int bb = 0; bb < 4; ++bb)
                    win[a * 4 + bb] = sp[base + a * 28 + bb];
#pragma unroll
            for (int co = 0; co < COUT_G; ++co) {
                const float* wp = wci + (size_t)co * CIN_G * 81 + e * 9;
#pragma unroll
                for (int d3 = 0; d3 < 3; ++d3)
#pragma unroll
                    for (int d4 = 0; d4 < 3; ++d4) {
                        float wv = wp[d3 * 3 + d4];
                        acc[co][0] = fmaf(win[d3 * 4 + d4],           wv, acc[co][0]);
                        acc[co][1] = fmaf(win[d3 * 4 + d4 + 1],       wv, acc[co][1]);
                        acc[co][2] = fmaf(win[(d3 + 1) * 4 + d4],     wv, acc[co][2]);
                        acc[co][3] = fmaf(win[(d3 + 1) * 4 + d4 + 1], wv, acc[co][3]);
                    }
            }
        }
    }

    if (tid < 169) {
#pragma unroll
        for (int co = 0; co < COUT_G; ++co) {
            float* op = out + (size_t)(g * COUT_G + co) * NPOSQ + f12 * 625;
#pragma unroll
            for (int i = 0; i < 2; ++i)
#pragma unroll
                for (int j = 0; j < 2; ++j) {
                    int f3 = r0 + i, f4 = c0 + j;
                    if (f3 < 25 && f4 < 25)
                        op[f3 * 25 + f4] = fmaxf(acc[co][i * 2 + j], 0.0f);
                }
        }
    }
}

// ---------------- launch ----------------
extern "C" void kernel_launch(void* const* d_in, const int* in_sizes, int n_in,
                              void* d_out, int out_size, void* d_ws, size_t ws_size,
                              hipStream_t stream)
{
    const float* fA = (const float*)d_in[0];
    const float* fB = (const float*)d_in[1];
    const float* W1 = (const float*)d_in[2];
    const float* b1 = (const float*)d_in[3];
    const float* W2 = (const float*)d_in[4];
    const float* b2 = (const float*)d_in[5];
    const float* W3 = (const float*)d_in[6];
    const float* b3 = (const float*)d_in[7];
    float* out = (float*)d_out;
    float* ws = (float*)d_ws;

    float* invA = ws + 0;        // 2500
    float* invB = ws + 2500;     // 2500
    float* rmax = ws + 5000;     // 2500
    float* cmax = ws + 7500;     // 2500
    float* WL1  = ws + 10000;    // 1620
    float* WL2  = ws + 11620;    // 16200
    float* WL3  = ws + 27820;    // 1620
    float* bL1  = ws + 29440;    // 20
    float* bL2  = ws + 29460;    // 20
    float* bL3  = ws + 29480;    // 2
    float* corr = ws + 40000;    // 1562500
    float* sbuf = ws + 1602504;  // 1562500
    float* x1   = ws + 3170000;  // 7812500  (20ch, one batch)
    float* x2   = ws + 11000000; // 7812500  (20ch, one batch)
    float* x3   = ws + 18820000; // 3125000  ([B][2][NPOSQ])

    hipLaunchKernelGGL(pack_weights_kernel, dim3(64), dim3(256), 0, stream,
                       W1, b1, W2, b2, W3, b3, WL1, WL2, WL3, bL1, bL2, bL3);
    hipLaunchKernelGGL(invnorm_kernel, dim3(10, 2), dim3(256), 0, stream, fA, fB, invA, invB);
    hipLaunchKernelGGL(corr_gemm_kernel, dim3(10, 10, 4), dim3(256), 0, stream,
                       fA, fB, invA, invB, corr);
    hipLaunchKernelGGL(rowmax_kernel, dim3(625), dim3(256), 0, stream, corr, rmax);
    hipLaunchKernelGGL(colmax_kernel, dim3(4, 5), dim3(128), 0, stream, corr, cmax);
    hipLaunchKernelGGL(mm_apply_kernel, dim3(6104), dim3(256), 0, stream, corr, rmax, cmax, corr);

    for (int b = 0; b < NB; ++b) {
        hipLaunchKernelGGL((conv4d_kernel<1, 20>), dim3(625, 1), dim3(192), 0, stream,
                           corr + (size_t)b * NPOSQ, WL1, bL1, x1);
        hipLaunchKernelGGL((conv4d_kernel<10, 10>), dim3(625, 2), dim3(192), 0, stream,
                           x1, WL2, bL2, x2);
        hipLaunchKernelGGL((conv4d_kernel<10, 1>), dim3(625, 2), dim3(192), 0, stream,
                           x2, WL3, bL3, x3 + (size_t)b * 2 * NPOSQ);
    }

    hipLaunchKernelGGL(sum2_kernel, dim3(6104), dim3(256), 0, stream, x3, sbuf);
    hipLaunchKernelGGL(rowmax_kernel, dim3(625), dim3(256), 0, stream, sbuf, rmax);
    hipLaunchKernelGGL(colmax_kernel, dim3(4, 5), dim3(128), 0, stream, sbuf, cmax);
    hipLaunchKernelGGL(mm_apply_kernel, dim3(6104), dim3(256), 0, stream, sbuf, rmax, cmax, out);
}